// Round 4
// baseline (444.332 us; speedup 1.0000x reference)
//
#include <hip/hip_runtime.h>
#include <hip/hip_bf16.h>

typedef __bf16 bf16x8 __attribute__((ext_vector_type(8)));
typedef float  floatx4 __attribute__((ext_vector_type(4)));
typedef float  floatx16 __attribute__((ext_vector_type(16)));

#define MFMA16(a, b, c) __builtin_amdgcn_mfma_f32_16x16x32_bf16((a), (b), (c), 0, 0, 0)
#define MFMA32(a, b, c) __builtin_amdgcn_mfma_f32_32x32x16_bf16((a), (b), (c), 0, 0, 0)

// Problem constants (B=4, S=4096, D=512, P=512)
static constexpr int BATCH = 4;
static constexpr int SEQ   = 4096;
static constexpr int MTOT  = BATCH * SEQ;  // 16384

// Async global->LDS DMA, 16B per lane (wave writes 1KB contiguous at ldst).
__device__ __forceinline__ void gload16(const void* gsrc, void* ldst)
{
    auto* g = reinterpret_cast<const __attribute__((address_space(1))) unsigned int*>(
        reinterpret_cast<unsigned long long>(gsrc));
    auto* l = reinterpret_cast<__attribute__((address_space(3))) unsigned int*>(
        reinterpret_cast<unsigned long long>(ldst));
    __builtin_amdgcn_global_load_lds(g, l, 16, 0, 0);
}

// ---------------------------------------------------------------------------
// Prep: x fp32 -> bf16 (row-major unchanged)
// ---------------------------------------------------------------------------
__global__ __launch_bounds__(256) void cvt_x(
    const float* __restrict__ x, __bf16* __restrict__ xb)
{
    const size_t i = ((size_t)blockIdx.x * 256 + threadIdx.x) * 8;
    const float4 a = *reinterpret_cast<const float4*>(x + i);
    const float4 c = *reinterpret_cast<const float4*>(x + i + 4);
    bf16x8 r;
    r[0] = (__bf16)a.x; r[1] = (__bf16)a.y; r[2] = (__bf16)a.z; r[3] = (__bf16)a.w;
    r[4] = (__bf16)c.x; r[5] = (__bf16)c.y; r[6] = (__bf16)c.z; r[7] = (__bf16)c.w;
    *reinterpret_cast<bf16x8*>(xb + i) = r;
}

// ---------------------------------------------------------------------------
// Prep: W [k][n] fp32 -> WT [n][k] bf16 (512x512), 64 blocks per matrix
// ---------------------------------------------------------------------------
__global__ __launch_bounds__(256) void transpose_w(
    const float* __restrict__ W, __bf16* __restrict__ WT)
{
    __shared__ __bf16 tile[64 * 68];
    const int t   = blockIdx.x;
    const int k0  = (t >> 3) * 64;
    const int n0  = (t & 7) * 64;
    const int tid = threadIdx.x;
#pragma unroll
    for (int it = 0; it < 4; ++it) {
        const int flat = it * 1024 + tid * 4;
        const int r = flat >> 6;   // k
        const int c = flat & 63;   // n
        const float4 v = *reinterpret_cast<const float4*>(
            W + (size_t)(k0 + r) * 512 + n0 + c);
        tile[r * 68 + c + 0] = (__bf16)v.x;
        tile[r * 68 + c + 1] = (__bf16)v.y;
        tile[r * 68 + c + 2] = (__bf16)v.z;
        tile[r * 68 + c + 3] = (__bf16)v.w;
    }
    __syncthreads();
#pragma unroll
    for (int it = 0; it < 2; ++it) {
        const int gid = it * 256 + tid;
        const int n  = gid >> 3;
        const int k8 = (gid & 7) * 8;
        bf16x8 r8;
#pragma unroll
        for (int j = 0; j < 8; ++j) r8[j] = tile[(k8 + j) * 68 + n];
        *reinterpret_cast<bf16x8*>(WT + (size_t)(n0 + n) * 512 + k0 + k8) = r8;
    }
}

// ---------------------------------------------------------------------------
// Fused QKV projection (all-bf16 inputs, gload_lds staging + XOR swizzle).
// Outputs are written in the FRAGMENT-MAJOR images flash_attn consumes:
//   Q: [(b*64+qblk)*2+rb][s][lane]  (B-frag image, 1KB blocks)
//   K: [(b*64+tt)*64 + kb*32+s][lane]  (A-frag image)
//   V: [(b*64+tt)*64 + pg*4+ks][lane]  (A-frag image)
// so flash's DMA is contiguous and its ds_reads are lane-linear (conflict-free).
// ---------------------------------------------------------------------------
__global__ __launch_bounds__(256, 2) void qkv_gemm(
    const __bf16* __restrict__ xb,
    const __bf16* __restrict__ WqT, const float* __restrict__ bq,
    const __bf16* __restrict__ WkT, const float* __restrict__ bk,
    const __bf16* __restrict__ WvT, const float* __restrict__ bv,
    __bf16* __restrict__ qb, __bf16* __restrict__ kb, __bf16* __restrict__ vb)
{
    __shared__ __attribute__((aligned(16))) __bf16 As[64 * 64];
    __shared__ __attribute__((aligned(16))) __bf16 Bq[64 * 64];
    __shared__ __attribute__((aligned(16))) __bf16 Bk[64 * 64];
    __shared__ __attribute__((aligned(16))) __bf16 Bv[64 * 64];
    __shared__ __bf16 Cs[64 * 80];

    const int tid  = threadIdx.x;
    const int w    = tid >> 6;
    const int lane = tid & 63;
    const int quad = lane >> 4;
    const int l15  = lane & 15;
    const int fid  = blockIdx.x;           // 0..2047
    const int n0   = (fid & 7) * 64;       // XCD-group = W column block
    const int m0   = (fid >> 3) * 64;

    const int srow0 = w * 8 + (lane >> 3);
    const int sgrp  = lane & 7;

    floatx4 aq[4], ak[4], av[4];
#pragma unroll
    for (int nt = 0; nt < 4; ++nt) {
        aq[nt] = floatx4{0.f, 0.f, 0.f, 0.f};
        ak[nt] = floatx4{0.f, 0.f, 0.f, 0.f};
        av[nt] = floatx4{0.f, 0.f, 0.f, 0.f};
    }

    for (int k0 = 0; k0 < 512; k0 += 64) {
#pragma unroll
        for (int i = 0; i < 2; ++i) {
            const int r  = i * 32 + srow0;
            const int cg = (sgrp ^ (r & 7)) << 3;
            const int db = (i * 32 + w * 8) * 64;
            gload16(xb  + (size_t)(m0 + r) * 512 + k0 + cg, &As[db]);
            gload16(WqT + (size_t)(n0 + r) * 512 + k0 + cg, &Bq[db]);
            gload16(WkT + (size_t)(n0 + r) * 512 + k0 + cg, &Bk[db]);
            gload16(WvT + (size_t)(n0 + r) * 512 + k0 + cg, &Bv[db]);
        }
        __syncthreads();

#pragma unroll
        for (int kk = 0; kk < 2; ++kk) {
            const int arow = w * 16 + l15;
            const bf16x8 af = *reinterpret_cast<const bf16x8*>(
                &As[arow * 64 + (((kk * 4 + quad) ^ (arow & 7)) << 3)]);
#pragma unroll
            for (int nt = 0; nt < 4; ++nt) {
                const int brow = nt * 16 + l15;
                const int off  = brow * 64 + (((kk * 4 + quad) ^ (brow & 7)) << 3);
                aq[nt] = MFMA16(af, *reinterpret_cast<const bf16x8*>(&Bq[off]), aq[nt]);
                ak[nt] = MFMA16(af, *reinterpret_cast<const bf16x8*>(&Bk[off]), ak[nt]);
                av[nt] = MFMA16(af, *reinterpret_cast<const bf16x8*>(&Bv[off]), av[nt]);
            }
        }
        __syncthreads();
    }

    // Epilogue: Q,K scalar stores into fragment-major images; V via Cs.
    const int b64q = (m0 >> 12) * 64 + ((m0 & 4095) >> 6);
#pragma unroll
    for (int nt = 0; nt < 4; ++nt) {
        const int col   = n0 + nt * 16 + l15;
        const int s_col = col >> 4;
        const int hcol  = l15 >> 3;
        const int jcol  = l15 & 7;
        const float bqv = bq[col], bkv = bk[col], bvv = bv[col];
#pragma unroll
        for (int r = 0; r < 4; ++r) {
            const int rr   = w * 16 + quad * 4 + r;
            const int lrow = rr & 31;
            const int rbt  = rr >> 5;
            const size_t qe = ((size_t)((b64q * 2 + rbt) * 32 + s_col) << 9)
                            + ((hcol * 32 + lrow) << 3) + jcol;
            const size_t ke = ((size_t)(b64q * 64 + rbt * 32 + s_col) << 9)
                            + ((hcol * 32 + lrow) << 3) + jcol;
            qb[qe] = (__bf16)((aq[nt][r] + bqv) * 0.125f);
            kb[ke] = (__bf16)(ak[nt][r] + bkv);
            Cs[(nt * 16 + l15) * 80 + rr] = (__bf16)(av[nt][r] + bvv);
        }
    }
    __syncthreads();
    {
#pragma unroll
        for (int it = 0; it < 2; ++it) {
            const int flat = it * 2048 + tid * 8;
            const int pl = flat >> 6;   // p-local 0..63
            const int c  = flat & 63;   // token-local, multiple of 8
            const bf16x8 vv = *reinterpret_cast<const bf16x8*>(&Cs[pl * 80 + c]);
            const int p = n0 + pl;
            const size_t ve = ((size_t)(b64q * 64 + (p >> 5) * 4 + (c >> 4)) << 9)
                            + ((((c >> 3) & 1) * 32 + (p & 31)) << 3);
            *reinterpret_cast<bf16x8*>(vb + ve) = vv;
        }
    }
}

// ---------------------------------------------------------------------------
// Output GEMM: out[M x 512] = attended(bf16) WoT^T + bo (fp32 out).
// ---------------------------------------------------------------------------
__global__ __launch_bounds__(256, 2) void out_gemm(
    const __bf16* __restrict__ A, const __bf16* __restrict__ WT,
    const float* __restrict__ bias, float* __restrict__ Y)
{
    __shared__ __attribute__((aligned(16))) __bf16 As[64 * 64];
    __shared__ __attribute__((aligned(16))) __bf16 Bs[64 * 64];

    const int tid  = threadIdx.x;
    const int w    = tid >> 6;
    const int lane = tid & 63;
    const int quad = lane >> 4;
    const int l15  = lane & 15;
    const int fid  = blockIdx.x;
    const int n0   = (fid & 7) * 64;
    const int m0   = (fid >> 3) * 64;

    const int srow0 = w * 8 + (lane >> 3);
    const int sgrp  = lane & 7;

    floatx4 acc[4];
#pragma unroll
    for (int nt = 0; nt < 4; ++nt) acc[nt] = floatx4{0.f, 0.f, 0.f, 0.f};

    for (int k0 = 0; k0 < 512; k0 += 64) {
#pragma unroll
        for (int i = 0; i < 2; ++i) {
            const int r  = i * 32 + srow0;
            const int cg = (sgrp ^ (r & 7)) << 3;
            const int db = (i * 32 + w * 8) * 64;
            gload16(A  + (size_t)(m0 + r) * 512 + k0 + cg, &As[db]);
            gload16(WT + (size_t)(n0 + r) * 512 + k0 + cg, &Bs[db]);
        }
        __syncthreads();

#pragma unroll
        for (int kk = 0; kk < 2; ++kk) {
            const int arow = w * 16 + l15;
            const bf16x8 af = *reinterpret_cast<const bf16x8*>(
                &As[arow * 64 + (((kk * 4 + quad) ^ (arow & 7)) << 3)]);
#pragma unroll
            for (int nt = 0; nt < 4; ++nt) {
                const int brow = nt * 16 + l15;
                const bf16x8 bfv = *reinterpret_cast<const bf16x8*>(
                    &Bs[brow * 64 + (((kk * 4 + quad) ^ (brow & 7)) << 3)]);
                acc[nt] = MFMA16(af, bfv, acc[nt]);
            }
        }
        __syncthreads();
    }

#pragma unroll
    for (int nt = 0; nt < 4; ++nt) {
        const int col = n0 + nt * 16 + l15;
        const float bv = bias[col];
#pragma unroll
        for (int r = 0; r < 4; ++r) {
            const int row = m0 + w * 16 + quad * 4 + r;
            Y[(size_t)row * 512 + col] = acc[nt][r] + bv;
        }
    }
}

// ---------------------------------------------------------------------------
// Flash attention, 32x32x16 MFMA, transposed-output, 8 waves, KVBLK=128.
//   S^T[key][qrow] = MFMA(A=K-frag, B=Q-frag)   (Q pre-scaled 0.125)
//   O^T[p][qrow]   = MFMA(A=V-frag, B=P-frag)
// Wave w: QK^T tile (kb=w&3, rb=w>>2); PV p-slice w*64..+64 (o = 64 VGPR).
// K staged in LDS (128KB, DMA, each block read by 2 waves); V read DIRECT
// from L2 (fragment-major => one wave, lane-linear); P in LDS (16KB).
// LDS 144KB -> 1 block/CU, but 8 waves = 2 waves/SIMD at <=256 VGPR.
// 16 iters per key-half; K(i+1) DMA flies under PV(i).
// ---------------------------------------------------------------------------
__global__ __launch_bounds__(512, 2) void flash_attn(
    const __bf16* __restrict__ qfg, const __bf16* __restrict__ kfg,
    const __bf16* __restrict__ vfg, __bf16* __restrict__ pO,
    float* __restrict__ lP)
{
    __shared__ __attribute__((aligned(16))) __bf16 SH[73728]; // 144KB
    __bf16* Kf = SH;            // 128 frag-blocks x 512 (128KB)
    __bf16* Pf = SH + 65536;    // 16 frag-blocks x 512 (16KB)

    const int tid  = threadIdx.x;
    const int w    = tid >> 6;      // 0..7
    const int lane = tid & 63;
    const int l31  = lane & 31;
    const int h    = lane >> 5;

    const int fid  = blockIdx.x;    // 0..511
    const int g    = fid & 7;       // XCD group = (batch, half)
    const int hb   = g & 1;
    const int b    = g >> 1;
    const int qblk = fid >> 3;      // 0..63
    const int kb   = w & 3;         // QKT key-block (32 keys of 128)
    const int rb   = w >> 2;        // QKT qrow-block (32 rows of 64)

    // Q B-frags for rows rb*32..+32 (lane: qrow=l31, k=(h*8)+j per step)
    bf16x8 qf[32];
    {
        const __bf16* qbase = qfg + ((size_t)((b * 64 + qblk) * 2 + rb) << 14)
                                  + (lane << 3);
#pragma unroll
        for (int s = 0; s < 32; ++s)
            qf[s] = *reinterpret_cast<const bf16x8*>(qbase + (s << 9));
    }

    floatx16 o[2][2];   // [pb][r2]: p = w*64+pb*32+row32, qrow = r2*32+l31
#pragma unroll
    for (int pb = 0; pb < 2; ++pb)
#pragma unroll
        for (int r2 = 0; r2 < 2; ++r2)
#pragma unroll
            for (int r = 0; r < 16; ++r) o[pb][r2][r] = 0.f;
    float lsum = 0.f;

    // K staging: wave w stages LDS frag-blocks [w*16, w*16+16).
    // LDS block kbl = kbK*32 + s (kbK = w>>1, s = (w&1)*16 + j);
    // global block = (b*64 + tt + (kbK>>1))*64 + (kbK&1)*32 + s.
    auto issueK = [&](int tt) {
        const int kbK = w >> 1;
        const __bf16* src = kfg + (((size_t)((b * 64 + tt + (kbK >> 1)) * 64
                            + (kbK & 1) * 32 + (w & 1) * 16)) << 9) + (lane << 3);
        __bf16* dst = &Kf[(size_t)(w * 16) << 9];
#pragma unroll
        for (int j = 0; j < 16; ++j)
            gload16(src + ((size_t)j << 9), dst + ((size_t)j << 9));
    };

    const int tt0 = hb * 32;        // token-64-group base of this key half
    issueK(tt0);

#pragma unroll 1
    for (int i = 0; i < 16; ++i) {
        const int tt = tt0 + i * 2;

        // ---- K(i) landed? own DMAs drained, then all waves' via barrier
        asm volatile("s_waitcnt vmcnt(0)" ::: "memory");
        __builtin_amdgcn_s_barrier();

        // ---- QK^T: S^T tile (kb, rb), k-dim 512 in 32 steps, 2 chains
        floatx16 s0, s1;
#pragma unroll
        for (int r = 0; r < 16; ++r) { s0[r] = 0.f; s1[r] = 0.f; }
        __builtin_amdgcn_s_setprio(1);
#pragma unroll
        for (int s = 0; s < 32; s += 2) {
            const bf16x8 a0 = *reinterpret_cast<const bf16x8*>(
                &Kf[((size_t)(kb * 32 + s) << 9) + (lane << 3)]);
            s0 = MFMA32(a0, qf[s], s0);
            const bf16x8 a1 = *reinterpret_cast<const bf16x8*>(
                &Kf[((size_t)(kb * 32 + s + 1) << 9) + (lane << 3)]);
            s1 = MFMA32(a1, qf[s + 1], s1);
        }
        __builtin_amdgcn_s_setprio(0);
        const floatx16 sv = s0 + s1;

        // ---- P = exp(s), lsum accumulate, P fragment-image store
#pragma unroll
        for (int r = 0; r < 16; ++r) {
            const float pv = __expf(sv[r]);
            lsum += pv;
            Pf[((rb * 8 + kb * 2 + (r >> 3)) << 9) + (((r >> 2) & 1) << 8)
               + (l31 << 3) + (r & 3) + 4 * h] = (__bf16)pv;
        }
        asm volatile("s_waitcnt lgkmcnt(0)" ::: "memory");
        __builtin_amdgcn_s_barrier();   // K(i) reads done; P(i) visible

        if (i + 1 < 16) issueK(tt0 + (i + 1) * 2);  // K(i+1) under PV(i)

        // ---- PV: o[pb][r2] += V(direct) . P(LDS), 8 key-steps of 16
        __builtin_amdgcn_s_setprio(1);
#pragma unroll
        for (int ks = 0; ks < 8; ++ks) {
            const bf16x8 p0 = *reinterpret_cast<const bf16x8*>(
                &Pf[((size_t)ks << 9) + (lane << 3)]);
            const bf16x8 p1 = *reinterpret_cast<const bf16x8*>(
                &Pf[((size_t)(8 + ks) << 9) + (lane << 3)]);
            const __bf16* vsrc = vfg
                + (((size_t)((b * 64 + tt + (ks >> 2)) * 64 + w * 8 + (ks & 3))) << 9)
                + (lane << 3);
            const bf16x8 av0 = *reinterpret_cast<const bf16x8*>(vsrc);
            const bf16x8 av1 = *reinterpret_cast<const bf16x8*>(vsrc + (4 << 9));
            o[0][0] = MFMA32(av0, p0, o[0][0]);
            o[0][1] = MFMA32(av0, p1, o[0][1]);
            o[1][0] = MFMA32(av1, p0, o[1][0]);
            o[1][1] = MFMA32(av1, p1, o[1][1]);
        }
        __builtin_amdgcn_s_setprio(0);
    }

    // ---- epilogue
    __builtin_amdgcn_s_barrier();   // all PV reads of Pf done

    // l: h-partner reduce; per-wave partials to LDS; cross-kb combine
    lsum += __shfl_xor(lsum, 32);
    float* Ls = (float*)Pf;
    if (lane < 32) Ls[w * 32 + l31] = lsum;

    // O^T -> Ot[qrow][p] (bf16, stride 520) over Kf region
    __bf16* Ot = SH;
#pragma unroll
    for (int pb = 0; pb < 2; ++pb)
#pragma unroll
        for (int r2 = 0; r2 < 2; ++r2)
#pragma unroll
            for (int r = 0; r < 16; ++r)
                Ot[(r2 * 32 + l31) * 520 + w * 64 + pb * 32
                   + (r & 3) + ((r >> 2) << 3) + 4 * h] = (__bf16)o[pb][r2][r];

    asm volatile("s_waitcnt lgkmcnt(0)" ::: "memory");
    __builtin_amdgcn_s_barrier();

    const int rowbase = b * SEQ + qblk * 64;
    if ((w & 3) == 0 && lane < 32) {    // w=0 -> rb 0, w=4 -> rb 1
        const int rbw = w >> 2;
        const float s = Ls[(rbw * 4 + 0) * 32 + l31] + Ls[(rbw * 4 + 1) * 32 + l31]
                      + Ls[(rbw * 4 + 2) * 32 + l31] + Ls[(rbw * 4 + 3) * 32 + l31];
        lP[(size_t)hb * MTOT + rowbase + rbw * 32 + l31] = s;
    }

    __bf16* pOh = pO + ((size_t)hb * MTOT << 9);
#pragma unroll
    for (int it = 0; it < 8; ++it) {
        const int id  = it * 512 + tid;
        const int row = id >> 6;
        const int gg  = id & 63;
        *reinterpret_cast<bf16x8*>(pOh + (size_t)(rowbase + row) * 512 + gg * 8) =
            *reinterpret_cast<const bf16x8*>(&Ot[row * 520 + gg * 8]);
    }
}

// ---------------------------------------------------------------------------
// Merge the two key-half partials: att = (O0 + O1) / (l0 + l1)
// ---------------------------------------------------------------------------
__global__ __launch_bounds__(256) void merge_attn(
    const __bf16* __restrict__ pO, const float* __restrict__ lP,
    __bf16* __restrict__ att)
{
    const int gidx = blockIdx.x * 256 + threadIdx.x;  // 8-elem group
    const int row  = gidx >> 6;
    const int c8   = (gidx & 63) * 8;
    const float li = 1.0f / (lP[row] + lP[MTOT + row]);
    const bf16x8 a = *reinterpret_cast<const bf16x8*>(&pO[(size_t)row * 512 + c8]);
    const bf16x8 bvv = *reinterpret_cast<const bf16x8*>(
        &pO[((size_t)MTOT + row) * 512 + c8]);
    bf16x8 r8;
#pragma unroll
    for (int j = 0; j < 8; ++j)
        r8[j] = (__bf16)(((float)a[j] + (float)bvv[j]) * li);
    *reinterpret_cast<bf16x8*>(&att[(size_t)row * 512 + c8]) = r8;
}

// ---------------------------------------------------------------------------
extern "C" void kernel_launch(void* const* d_in, const int* in_sizes, int n_in,
                              void* d_out, int out_size, void* d_ws, size_t ws_size,
                              hipStream_t stream)
{
    (void)in_sizes; (void)n_in; (void)out_size; (void)ws_size;

    const float* x  = (const float*)d_in[0];
    const float* Wq = (const float*)d_in[1];
    const float* bq = (const float*)d_in[2];
    const float* Wk = (const float*)d_in[3];
    const float* bk = (const float*)d_in[4];
    const float* Wv = (const float*)d_in[5];
    const float* bv = (const float*)d_in[6];
    const float* Wo = (const float*)d_in[7];
    const float* bo = (const float*)d_in[8];
    float* out = (float*)d_out;

    // ws (48.1 MB): qb, kb, vb (16 MB each, fragment-major) + lP.
    // xb + WqT/WkT/WvT live in d_out (dead before pO written);
    // WoT lives in kb (dead after flash); ab overlays qb.
    __bf16* qb  = (__bf16*)d_ws;
    __bf16* kb  = qb  + (size_t)MTOT * 512;
    __bf16* vb  = kb  + (size_t)MTOT * 512;
    float*  lP  = (float*)(vb + (size_t)MTOT * 512);
    __bf16* pO  = (__bf16*)d_out;
    __bf16* ab  = qb;

    __bf16* xb  = (__bf16*)d_out;
    __bf16* WqT = xb  + (size_t)MTOT * 512;
    __bf16* WkT = WqT + 512 * 512;
    __bf16* WvT = WkT + 512 * 512;
    __bf16* WoT = kb;

    cvt_x<<<MTOT * 512 / 2048, 256, 0, stream>>>(x, xb);
    transpose_w<<<64, 256, 0, stream>>>(Wq, WqT);
    transpose_w<<<64, 256, 0, stream>>>(Wk, WkT);
    transpose_w<<<64, 256, 0, stream>>>(Wv, WvT);

    qkv_gemm<<<2048, 256, 0, stream>>>(xb, WqT, bq, WkT, bk, WvT, bv, qb, kb, vb);

    flash_attn<<<512, 512, 0, stream>>>(qb, kb, vb, pO, lP);

    transpose_w<<<64, 256, 0, stream>>>(Wo, WoT);
    merge_attn<<<MTOT * 64 / 256, 256, 0, stream>>>(pO, lP, ab);

    out_gemm<<<2048, 256, 0, stream>>>(ab, WoT, bo, out);
}

// Round 5
// 442.884 us; speedup vs baseline: 1.0033x; 1.0033x over previous
//
#include <hip/hip_runtime.h>
#include <hip/hip_bf16.h>

typedef __bf16 bf16x8 __attribute__((ext_vector_type(8)));
typedef float  floatx4 __attribute__((ext_vector_type(4)));
typedef float  floatx16 __attribute__((ext_vector_type(16)));

#define MFMA16(a, b, c) __builtin_amdgcn_mfma_f32_16x16x32_bf16((a), (b), (c), 0, 0, 0)
#define MFMA32(a, b, c) __builtin_amdgcn_mfma_f32_32x32x16_bf16((a), (b), (c), 0, 0, 0)

// Problem constants (B=4, S=4096, D=512, P=512)
static constexpr int BATCH = 4;
static constexpr int SEQ   = 4096;
static constexpr int MTOT  = BATCH * SEQ;  // 16384

// Async global->LDS DMA, 16B per lane (wave writes 1KB contiguous at ldst).
__device__ __forceinline__ void gload16(const void* gsrc, void* ldst)
{
    auto* g = reinterpret_cast<const __attribute__((address_space(1))) unsigned int*>(
        reinterpret_cast<unsigned long long>(gsrc));
    auto* l = reinterpret_cast<__attribute__((address_space(3))) unsigned int*>(
        reinterpret_cast<unsigned long long>(ldst));
    __builtin_amdgcn_global_load_lds(g, l, 16, 0, 0);
}

// ---------------------------------------------------------------------------
// Prep: x fp32 -> bf16 (row-major unchanged)
// ---------------------------------------------------------------------------
__global__ __launch_bounds__(256) void cvt_x(
    const float* __restrict__ x, __bf16* __restrict__ xb)
{
    const size_t i = ((size_t)blockIdx.x * 256 + threadIdx.x) * 8;
    const float4 a = *reinterpret_cast<const float4*>(x + i);
    const float4 c = *reinterpret_cast<const float4*>(x + i + 4);
    bf16x8 r;
    r[0] = (__bf16)a.x; r[1] = (__bf16)a.y; r[2] = (__bf16)a.z; r[3] = (__bf16)a.w;
    r[4] = (__bf16)c.x; r[5] = (__bf16)c.y; r[6] = (__bf16)c.z; r[7] = (__bf16)c.w;
    *reinterpret_cast<bf16x8*>(xb + i) = r;
}

// ---------------------------------------------------------------------------
// Prep: W [k][n] fp32 -> WT [n][k] bf16 (512x512), 64 blocks per matrix
// ---------------------------------------------------------------------------
__global__ __launch_bounds__(256) void transpose_w(
    const float* __restrict__ W, __bf16* __restrict__ WT)
{
    __shared__ __bf16 tile[64 * 68];
    const int t   = blockIdx.x;
    const int k0  = (t >> 3) * 64;
    const int n0  = (t & 7) * 64;
    const int tid = threadIdx.x;
#pragma unroll
    for (int it = 0; it < 4; ++it) {
        const int flat = it * 1024 + tid * 4;
        const int r = flat >> 6;   // k
        const int c = flat & 63;   // n
        const float4 v = *reinterpret_cast<const float4*>(
            W + (size_t)(k0 + r) * 512 + n0 + c);
        tile[r * 68 + c + 0] = (__bf16)v.x;
        tile[r * 68 + c + 1] = (__bf16)v.y;
        tile[r * 68 + c + 2] = (__bf16)v.z;
        tile[r * 68 + c + 3] = (__bf16)v.w;
    }
    __syncthreads();
#pragma unroll
    for (int it = 0; it < 2; ++it) {
        const int gid = it * 256 + tid;
        const int n  = gid >> 3;
        const int k8 = (gid & 7) * 8;
        bf16x8 r8;
#pragma unroll
        for (int j = 0; j < 8; ++j) r8[j] = tile[(k8 + j) * 68 + n];
        *reinterpret_cast<bf16x8*>(WT + (size_t)(n0 + n) * 512 + k0 + k8) = r8;
    }
}

// ---------------------------------------------------------------------------
// Fused QKV projection (all-bf16 inputs, gload_lds staging + XOR swizzle).
// Outputs are written in the FRAGMENT-MAJOR images flash_attn consumes:
//   Q: [(b*64+qblk)*2+rb][s][lane]  (B-frag image, 1KB blocks)
//   K: [(b*64+tt)*64 + kb*32+s][lane]  (A-frag image)
//   V: [(b*64+tt)*64 + pg*4+ks][lane]  (A-frag image)
// so flash's DMA is contiguous and its ds_reads are lane-linear (conflict-free).
// ---------------------------------------------------------------------------
__global__ __launch_bounds__(256, 2) void qkv_gemm(
    const __bf16* __restrict__ xb,
    const __bf16* __restrict__ WqT, const float* __restrict__ bq,
    const __bf16* __restrict__ WkT, const float* __restrict__ bk,
    const __bf16* __restrict__ WvT, const float* __restrict__ bv,
    __bf16* __restrict__ qb, __bf16* __restrict__ kb, __bf16* __restrict__ vb)
{
    __shared__ __attribute__((aligned(16))) __bf16 As[64 * 64];
    __shared__ __attribute__((aligned(16))) __bf16 Bq[64 * 64];
    __shared__ __attribute__((aligned(16))) __bf16 Bk[64 * 64];
    __shared__ __attribute__((aligned(16))) __bf16 Bv[64 * 64];
    __shared__ __bf16 Cs[64 * 80];

    const int tid  = threadIdx.x;
    const int w    = tid >> 6;
    const int lane = tid & 63;
    const int quad = lane >> 4;
    const int l15  = lane & 15;
    const int fid  = blockIdx.x;           // 0..2047
    const int n0   = (fid & 7) * 64;       // XCD-group = W column block
    const int m0   = (fid >> 3) * 64;

    const int srow0 = w * 8 + (lane >> 3);
    const int sgrp  = lane & 7;

    floatx4 aq[4], ak[4], av[4];
#pragma unroll
    for (int nt = 0; nt < 4; ++nt) {
        aq[nt] = floatx4{0.f, 0.f, 0.f, 0.f};
        ak[nt] = floatx4{0.f, 0.f, 0.f, 0.f};
        av[nt] = floatx4{0.f, 0.f, 0.f, 0.f};
    }

    for (int k0 = 0; k0 < 512; k0 += 64) {
#pragma unroll
        for (int i = 0; i < 2; ++i) {
            const int r  = i * 32 + srow0;
            const int cg = (sgrp ^ (r & 7)) << 3;
            const int db = (i * 32 + w * 8) * 64;
            gload16(xb  + (size_t)(m0 + r) * 512 + k0 + cg, &As[db]);
            gload16(WqT + (size_t)(n0 + r) * 512 + k0 + cg, &Bq[db]);
            gload16(WkT + (size_t)(n0 + r) * 512 + k0 + cg, &Bk[db]);
            gload16(WvT + (size_t)(n0 + r) * 512 + k0 + cg, &Bv[db]);
        }
        __syncthreads();

#pragma unroll
        for (int kk = 0; kk < 2; ++kk) {
            const int arow = w * 16 + l15;
            const bf16x8 af = *reinterpret_cast<const bf16x8*>(
                &As[arow * 64 + (((kk * 4 + quad) ^ (arow & 7)) << 3)]);
#pragma unroll
            for (int nt = 0; nt < 4; ++nt) {
                const int brow = nt * 16 + l15;
                const int off  = brow * 64 + (((kk * 4 + quad) ^ (brow & 7)) << 3);
                aq[nt] = MFMA16(af, *reinterpret_cast<const bf16x8*>(&Bq[off]), aq[nt]);
                ak[nt] = MFMA16(af, *reinterpret_cast<const bf16x8*>(&Bk[off]), ak[nt]);
                av[nt] = MFMA16(af, *reinterpret_cast<const bf16x8*>(&Bv[off]), av[nt]);
            }
        }
        __syncthreads();
    }

    // Epilogue: Q,K scalar stores into fragment-major images; V via Cs.
    const int b64q = (m0 >> 12) * 64 + ((m0 & 4095) >> 6);
#pragma unroll
    for (int nt = 0; nt < 4; ++nt) {
        const int col   = n0 + nt * 16 + l15;
        const int s_col = col >> 4;
        const int hcol  = l15 >> 3;
        const int jcol  = l15 & 7;
        const float bqv = bq[col], bkv = bk[col], bvv = bv[col];
#pragma unroll
        for (int r = 0; r < 4; ++r) {
            const int rr   = w * 16 + quad * 4 + r;
            const int lrow = rr & 31;
            const int rbt  = rr >> 5;
            const size_t qe = ((size_t)((b64q * 2 + rbt) * 32 + s_col) << 9)
                            + ((hcol * 32 + lrow) << 3) + jcol;
            const size_t ke = ((size_t)(b64q * 64 + rbt * 32 + s_col) << 9)
                            + ((hcol * 32 + lrow) << 3) + jcol;
            qb[qe] = (__bf16)((aq[nt][r] + bqv) * 0.125f);
            kb[ke] = (__bf16)(ak[nt][r] + bkv);
            Cs[(nt * 16 + l15) * 80 + rr] = (__bf16)(av[nt][r] + bvv);
        }
    }
    __syncthreads();
    {
#pragma unroll
        for (int it = 0; it < 2; ++it) {
            const int flat = it * 2048 + tid * 8;
            const int pl = flat >> 6;   // p-local 0..63
            const int c  = flat & 63;   // token-local, multiple of 8
            const bf16x8 vv = *reinterpret_cast<const bf16x8*>(&Cs[pl * 80 + c]);
            const int p = n0 + pl;
            const size_t ve = ((size_t)(b64q * 64 + (p >> 5) * 4 + (c >> 4)) << 9)
                            + ((((c >> 3) & 1) * 32 + (p & 31)) << 3);
            *reinterpret_cast<bf16x8*>(vb + ve) = vv;
        }
    }
}

// ---------------------------------------------------------------------------
// Output GEMM: out[M x 512] = attended(bf16) WoT^T + bo (fp32 out).
// ---------------------------------------------------------------------------
__global__ __launch_bounds__(256, 2) void out_gemm(
    const __bf16* __restrict__ A, const __bf16* __restrict__ WT,
    const float* __restrict__ bias, float* __restrict__ Y)
{
    __shared__ __attribute__((aligned(16))) __bf16 As[64 * 64];
    __shared__ __attribute__((aligned(16))) __bf16 Bs[64 * 64];

    const int tid  = threadIdx.x;
    const int w    = tid >> 6;
    const int lane = tid & 63;
    const int quad = lane >> 4;
    const int l15  = lane & 15;
    const int fid  = blockIdx.x;
    const int n0   = (fid & 7) * 64;
    const int m0   = (fid >> 3) * 64;

    const int srow0 = w * 8 + (lane >> 3);
    const int sgrp  = lane & 7;

    floatx4 acc[4];
#pragma unroll
    for (int nt = 0; nt < 4; ++nt) acc[nt] = floatx4{0.f, 0.f, 0.f, 0.f};

    for (int k0 = 0; k0 < 512; k0 += 64) {
#pragma unroll
        for (int i = 0; i < 2; ++i) {
            const int r  = i * 32 + srow0;
            const int cg = (sgrp ^ (r & 7)) << 3;
            const int db = (i * 32 + w * 8) * 64;
            gload16(A  + (size_t)(m0 + r) * 512 + k0 + cg, &As[db]);
            gload16(WT + (size_t)(n0 + r) * 512 + k0 + cg, &Bs[db]);
        }
        __syncthreads();

#pragma unroll
        for (int kk = 0; kk < 2; ++kk) {
            const int arow = w * 16 + l15;
            const bf16x8 af = *reinterpret_cast<const bf16x8*>(
                &As[arow * 64 + (((kk * 4 + quad) ^ (arow & 7)) << 3)]);
#pragma unroll
            for (int nt = 0; nt < 4; ++nt) {
                const int brow = nt * 16 + l15;
                const bf16x8 bfv = *reinterpret_cast<const bf16x8*>(
                    &Bs[brow * 64 + (((kk * 4 + quad) ^ (brow & 7)) << 3)]);
                acc[nt] = MFMA16(af, bfv, acc[nt]);
            }
        }
        __syncthreads();
    }

#pragma unroll
    for (int nt = 0; nt < 4; ++nt) {
        const int col = n0 + nt * 16 + l15;
        const float bv = bias[col];
#pragma unroll
        for (int r = 0; r < 4; ++r) {
            const int row = m0 + w * 16 + quad * 4 + r;
            Y[(size_t)row * 512 + col] = acc[nt][r] + bv;
        }
    }
}

// ---------------------------------------------------------------------------
// Flash attention, 32x32x16 MFMA, transposed-output, 8 waves, KVBLK=128.
//   S^T[key][qrow] = MFMA(A=K-frag, B=Q-frag)   (Q pre-scaled 0.125)
//   O^T[p][qrow]   = MFMA(A=V-frag, B=P-frag)
// Wave w: QK^T tile (kb=w&3, rb=w>>2); PV p-slice w*64..+64 (o = 64 VGPR).
// K staged in LDS (128KB, DMA); V read DIRECT from L2 (fragment-major,
// lane-linear); P in LDS (16KB). LDS 144KB -> 1 block/CU, 8 waves = 2/SIMD.
// NOTE __launch_bounds__(512, 1): the 2nd arg behaves as min BLOCKS/CU
// (CUDA semantics) — (512,2) capped VGPR at 128 and spilled qf[32] (R4:
// VGPR_Count=128, flash 272us). (512,1) -> 256-VGPR cap, qf resident.
// ---------------------------------------------------------------------------
__global__ __launch_bounds__(512, 1) void flash_attn(
    const __bf16* __restrict__ qfg, const __bf16* __restrict__ kfg,
    const __bf16* __restrict__ vfg, __bf16* __restrict__ pO,
    float* __restrict__ lP)
{
    __shared__ __attribute__((aligned(16))) __bf16 SH[73728]; // 144KB
    __bf16* Kf = SH;            // 128 frag-blocks x 512 (128KB)
    __bf16* Pf = SH + 65536;    // 16 frag-blocks x 512 (16KB)

    const int tid  = threadIdx.x;
    const int w    = tid >> 6;      // 0..7
    const int lane = tid & 63;
    const int l31  = lane & 31;
    const int h    = lane >> 5;

    const int fid  = blockIdx.x;    // 0..511
    const int g    = fid & 7;       // XCD group = (batch, half)
    const int hb   = g & 1;
    const int b    = g >> 1;
    const int qblk = fid >> 3;      // 0..63
    const int kb   = w & 3;         // QKT key-block (32 keys of 128)
    const int rb   = w >> 2;        // QKT qrow-block (32 rows of 64)

    // Q B-frags for rows rb*32..+32 (lane: qrow=l31, k=(h*8)+j per step)
    bf16x8 qf[32];
    {
        const __bf16* qbase = qfg + ((size_t)((b * 64 + qblk) * 2 + rb) << 14)
                                  + (lane << 3);
#pragma unroll
        for (int s = 0; s < 32; ++s)
            qf[s] = *reinterpret_cast<const bf16x8*>(qbase + (s << 9));
    }

    floatx16 o[2][2];   // [pb][r2]: p = w*64+pb*32+row32, qrow = r2*32+l31
#pragma unroll
    for (int pb = 0; pb < 2; ++pb)
#pragma unroll
        for (int r2 = 0; r2 < 2; ++r2)
#pragma unroll
            for (int r = 0; r < 16; ++r) o[pb][r2][r] = 0.f;
    float lsum = 0.f;

    // K staging: wave w stages LDS frag-blocks [w*16, w*16+16).
    // LDS block kbl = kbK*32 + s (kbK = w>>1, s = (w&1)*16 + j);
    // global block = (b*64 + tt + (kbK>>1))*64 + (kbK&1)*32 + s.
    auto issueK = [&](int tt) {
        const int kbK = w >> 1;
        const __bf16* src = kfg + (((size_t)((b * 64 + tt + (kbK >> 1)) * 64
                            + (kbK & 1) * 32 + (w & 1) * 16)) << 9) + (lane << 3);
        __bf16* dst = &Kf[(size_t)(w * 16) << 9];
#pragma unroll
        for (int j = 0; j < 16; ++j)
            gload16(src + ((size_t)j << 9), dst + ((size_t)j << 9));
    };

    const int tt0 = hb * 32;        // token-64-group base of this key half
    issueK(tt0);

#pragma unroll 1
    for (int i = 0; i < 16; ++i) {
        const int tt = tt0 + i * 2;

        // ---- K(i) landed? own DMAs drained, then all waves' via barrier
        asm volatile("s_waitcnt vmcnt(0)" ::: "memory");
        __builtin_amdgcn_s_barrier();

        // ---- QK^T: S^T tile (kb, rb), k-dim 512 in 32 steps, 2 chains
        floatx16 s0, s1;
#pragma unroll
        for (int r = 0; r < 16; ++r) { s0[r] = 0.f; s1[r] = 0.f; }
        __builtin_amdgcn_s_setprio(1);
#pragma unroll
        for (int s = 0; s < 32; s += 2) {
            const bf16x8 a0 = *reinterpret_cast<const bf16x8*>(
                &Kf[((size_t)(kb * 32 + s) << 9) + (lane << 3)]);
            s0 = MFMA32(a0, qf[s], s0);
            const bf16x8 a1 = *reinterpret_cast<const bf16x8*>(
                &Kf[((size_t)(kb * 32 + s + 1) << 9) + (lane << 3)]);
            s1 = MFMA32(a1, qf[s + 1], s1);
        }
        __builtin_amdgcn_s_setprio(0);
        const floatx16 sv = s0 + s1;

        // ---- P = exp(s), lsum accumulate, P fragment-image store
#pragma unroll
        for (int r = 0; r < 16; ++r) {
            const float pv = __expf(sv[r]);
            lsum += pv;
            Pf[((rb * 8 + kb * 2 + (r >> 3)) << 9) + (((r >> 2) & 1) << 8)
               + (l31 << 3) + (r & 3) + 4 * h] = (__bf16)pv;
        }
        asm volatile("s_waitcnt lgkmcnt(0)" ::: "memory");
        __builtin_amdgcn_s_barrier();   // K(i) reads done; P(i) visible

        if (i + 1 < 16) issueK(tt0 + (i + 1) * 2);  // K(i+1) under PV(i)

        // ---- PV: o[pb][r2] += V(direct) . P(LDS), 8 key-steps of 16
        __builtin_amdgcn_s_setprio(1);
#pragma unroll
        for (int ks = 0; ks < 8; ++ks) {
            const bf16x8 p0 = *reinterpret_cast<const bf16x8*>(
                &Pf[((size_t)ks << 9) + (lane << 3)]);
            const bf16x8 p1 = *reinterpret_cast<const bf16x8*>(
                &Pf[((size_t)(8 + ks) << 9) + (lane << 3)]);
            const __bf16* vsrc = vfg
                + (((size_t)((b * 64 + tt + (ks >> 2)) * 64 + w * 8 + (ks & 3))) << 9)
                + (lane << 3);
            const bf16x8 av0 = *reinterpret_cast<const bf16x8*>(vsrc);
            const bf16x8 av1 = *reinterpret_cast<const bf16x8*>(vsrc + (4 << 9));
            o[0][0] = MFMA32(av0, p0, o[0][0]);
            o[0][1] = MFMA32(av0, p1, o[0][1]);
            o[1][0] = MFMA32(av1, p0, o[1][0]);
            o[1][1] = MFMA32(av1, p1, o[1][1]);
        }
        __builtin_amdgcn_s_setprio(0);
    }

    // ---- epilogue
    __builtin_amdgcn_s_barrier();   // all PV reads of Pf done

    // l: h-partner reduce; per-wave partials to LDS; cross-kb combine
    lsum += __shfl_xor(lsum, 32);
    float* Ls = (float*)Pf;
    if (lane < 32) Ls[w * 32 + l31] = lsum;

    // O^T -> Ot[qrow][p] (bf16, stride 520) over Kf region
    __bf16* Ot = SH;
#pragma unroll
    for (int pb = 0; pb < 2; ++pb)
#pragma unroll
        for (int r2 = 0; r2 < 2; ++r2)
#pragma unroll
            for (int r = 0; r < 16; ++r)
                Ot[(r2 * 32 + l31) * 520 + w * 64 + pb * 32
                   + (r & 3) + ((r >> 2) << 3) + 4 * h] = (__bf16)o[pb][r2][r];

    asm volatile("s_waitcnt lgkmcnt(0)" ::: "memory");
    __builtin_amdgcn_s_barrier();

    const int rowbase = b * SEQ + qblk * 64;
    if ((w & 3) == 0 && lane < 32) {    // w=0 -> rb 0, w=4 -> rb 1
        const int rbw = w >> 2;
        const float s = Ls[(rbw * 4 + 0) * 32 + l31] + Ls[(rbw * 4 + 1) * 32 + l31]
                      + Ls[(rbw * 4 + 2) * 32 + l31] + Ls[(rbw * 4 + 3) * 32 + l31];
        lP[(size_t)hb * MTOT + rowbase + rbw * 32 + l31] = s;
    }

    __bf16* pOh = pO + ((size_t)hb * MTOT << 9);
#pragma unroll
    for (int it = 0; it < 8; ++it) {
        const int id  = it * 512 + tid;
        const int row = id >> 6;
        const int gg  = id & 63;
        *reinterpret_cast<bf16x8*>(pOh + (size_t)(rowbase + row) * 512 + gg * 8) =
            *reinterpret_cast<const bf16x8*>(&Ot[row * 520 + gg * 8]);
    }
}

// ---------------------------------------------------------------------------
// Merge the two key-half partials: att = (O0 + O1) / (l0 + l1)
// ---------------------------------------------------------------------------
__global__ __launch_bounds__(256) void merge_attn(
    const __bf16* __restrict__ pO, const float* __restrict__ lP,
    __bf16* __restrict__ att)
{
    const int gidx = blockIdx.x * 256 + threadIdx.x;  // 8-elem group
    const int row  = gidx >> 6;
    const int c8   = (gidx & 63) * 8;
    const float li = 1.0f / (lP[row] + lP[MTOT + row]);
    const bf16x8 a = *reinterpret_cast<const bf16x8*>(&pO[(size_t)row * 512 + c8]);
    const bf16x8 bvv = *reinterpret_cast<const bf16x8*>(
        &pO[((size_t)MTOT + row) * 512 + c8]);
    bf16x8 r8;
#pragma unroll
    for (int j = 0; j < 8; ++j)
        r8[j] = (__bf16)(((float)a[j] + (float)bvv[j]) * li);
    *reinterpret_cast<bf16x8*>(&att[(size_t)row * 512 + c8]) = r8;
}

// ---------------------------------------------------------------------------
extern "C" void kernel_launch(void* const* d_in, const int* in_sizes, int n_in,
                              void* d_out, int out_size, void* d_ws, size_t ws_size,
                              hipStream_t stream)
{
    (void)in_sizes; (void)n_in; (void)out_size; (void)ws_size;

    const float* x  = (const float*)d_in[0];
    const float* Wq = (const float*)d_in[1];
    const float* bq = (const float*)d_in[2];
    const float* Wk = (const float*)d_in[3];
    const float* bk = (const float*)d_in[4];
    const float* Wv = (const float*)d_in[5];
    const float* bv = (const float*)d_in[6];
    const float* Wo = (const float*)d_in[7];
    const float* bo = (const float*)d_in[8];
    float* out = (float*)d_out;

    // ws (48.1 MB): qb, kb, vb (16 MB each, fragment-major) + lP.
    // xb + WqT/WkT/WvT live in d_out (dead before pO written);
    // WoT lives in kb (dead after flash); ab overlays qb.
    __bf16* qb  = (__bf16*)d_ws;
    __bf16* kb  = qb  + (size_t)MTOT * 512;
    __bf16* vb  = kb  + (size_t)MTOT * 512;
    float*  lP  = (float*)(vb + (size_t)MTOT * 512);
    __bf16* pO  = (__bf16*)d_out;
    __bf16* ab  = qb;

    __bf16* xb  = (__bf16*)d_out;
    __bf16* WqT = xb  + (size_t)MTOT * 512;
    __bf16* WkT = WqT + 512 * 512;
    __bf16* WvT = WkT + 512 * 512;
    __bf16* WoT = kb;

    cvt_x<<<MTOT * 512 / 2048, 256, 0, stream>>>(x, xb);
    transpose_w<<<64, 256, 0, stream>>>(Wq, WqT);
    transpose_w<<<64, 256, 0, stream>>>(Wk, WkT);
    transpose_w<<<64, 256, 0, stream>>>(Wv, WvT);

    qkv_gemm<<<2048, 256, 0, stream>>>(xb, WqT, bq, WkT, bk, WvT, bv, qb, kb, vb);

    flash_attn<<<512, 512, 0, stream>>>(qb, kb, vb, pO, lP);

    transpose_w<<<64, 256, 0, stream>>>(Wo, WoT);
    merge_attn<<<MTOT * 64 / 256, 256, 0, stream>>>(pO, lP, ab);

    out_gemm<<<2048, 256, 0, stream>>>(ab, WoT, bo, out);
}

// Round 6
// 340.228 us; speedup vs baseline: 1.3060x; 1.3017x over previous
//
#include <hip/hip_runtime.h>
#include <hip/hip_bf16.h>

typedef __bf16 bf16x8 __attribute__((ext_vector_type(8)));
typedef float  floatx4 __attribute__((ext_vector_type(4)));

#define MFMA16(a, b, c) __builtin_amdgcn_mfma_f32_16x16x32_bf16((a), (b), (c), 0, 0, 0)

// Problem constants (B=4, S=4096, D=512, P=512)
static constexpr int BATCH = 4;
static constexpr int SEQ   = 4096;
static constexpr int MTOT  = BATCH * SEQ;  // 16384

// Async global->LDS DMA, 16B per lane (wave writes 1KB contiguous at ldst).
__device__ __forceinline__ void gload16(const void* gsrc, void* ldst)
{
    auto* g = reinterpret_cast<const __attribute__((address_space(1))) unsigned int*>(
        reinterpret_cast<unsigned long long>(gsrc));
    auto* l = reinterpret_cast<__attribute__((address_space(3))) unsigned int*>(
        reinterpret_cast<unsigned long long>(ldst));
    __builtin_amdgcn_global_load_lds(g, l, 16, 0, 0);
}

// ---------------------------------------------------------------------------
// Prep: x fp32 -> bf16 (row-major unchanged)
// ---------------------------------------------------------------------------
__global__ __launch_bounds__(256) void cvt_x(
    const float* __restrict__ x, __bf16* __restrict__ xb)
{
    const size_t i = ((size_t)blockIdx.x * 256 + threadIdx.x) * 8;
    const float4 a = *reinterpret_cast<const float4*>(x + i);
    const float4 c = *reinterpret_cast<const float4*>(x + i + 4);
    bf16x8 r;
    r[0] = (__bf16)a.x; r[1] = (__bf16)a.y; r[2] = (__bf16)a.z; r[3] = (__bf16)a.w;
    r[4] = (__bf16)c.x; r[5] = (__bf16)c.y; r[6] = (__bf16)c.z; r[7] = (__bf16)c.w;
    *reinterpret_cast<bf16x8*>(xb + i) = r;
}

// ---------------------------------------------------------------------------
// Prep: W [k][n] fp32 -> WT [n][k] bf16 (512x512), 64 blocks per matrix
// ---------------------------------------------------------------------------
__global__ __launch_bounds__(256) void transpose_w(
    const float* __restrict__ W, __bf16* __restrict__ WT)
{
    __shared__ __bf16 tile[64 * 68];
    const int t   = blockIdx.x;
    const int k0  = (t >> 3) * 64;
    const int n0  = (t & 7) * 64;
    const int tid = threadIdx.x;
#pragma unroll
    for (int it = 0; it < 4; ++it) {
        const int flat = it * 1024 + tid * 4;
        const int r = flat >> 6;   // k
        const int c = flat & 63;   // n
        const float4 v = *reinterpret_cast<const float4*>(
            W + (size_t)(k0 + r) * 512 + n0 + c);
        tile[r * 68 + c + 0] = (__bf16)v.x;
        tile[r * 68 + c + 1] = (__bf16)v.y;
        tile[r * 68 + c + 2] = (__bf16)v.z;
        tile[r * 68 + c + 3] = (__bf16)v.w;
    }
    __syncthreads();
#pragma unroll
    for (int it = 0; it < 2; ++it) {
        const int gid = it * 256 + tid;
        const int n  = gid >> 3;
        const int k8 = (gid & 7) * 8;
        bf16x8 r8;
#pragma unroll
        for (int j = 0; j < 8; ++j) r8[j] = tile[(k8 + j) * 68 + n];
        *reinterpret_cast<bf16x8*>(WT + (size_t)(n0 + n) * 512 + k0 + k8) = r8;
    }
}

// ---------------------------------------------------------------------------
// Fused QKV projection (all-bf16 inputs, gload_lds staging + XOR swizzle):
// Q = 0.125*(xb WqT^T + bq), K = xb WkT^T + bk, V -> vbT[b][p][t].
// Row-major qb/kb (the R2 layout the 16x16 flash consumes).
// ---------------------------------------------------------------------------
__global__ __launch_bounds__(256, 2) void qkv_gemm(
    const __bf16* __restrict__ xb,
    const __bf16* __restrict__ WqT, const float* __restrict__ bq,
    const __bf16* __restrict__ WkT, const float* __restrict__ bk,
    const __bf16* __restrict__ WvT, const float* __restrict__ bv,
    __bf16* __restrict__ qb, __bf16* __restrict__ kb, __bf16* __restrict__ vbT)
{
    __shared__ __attribute__((aligned(16))) __bf16 As[64 * 64];
    __shared__ __attribute__((aligned(16))) __bf16 Bq[64 * 64];
    __shared__ __attribute__((aligned(16))) __bf16 Bk[64 * 64];
    __shared__ __attribute__((aligned(16))) __bf16 Bv[64 * 64];
    __shared__ __bf16 Cs[64 * 80];

    const int tid  = threadIdx.x;
    const int w    = tid >> 6;
    const int lane = tid & 63;
    const int quad = lane >> 4;
    const int l15  = lane & 15;
    const int fid  = blockIdx.x;           // 0..2047
    const int n0   = (fid & 7) * 64;       // XCD-group = W column block
    const int m0   = (fid >> 3) * 64;

    const int srow0 = w * 8 + (lane >> 3);
    const int sgrp  = lane & 7;

    floatx4 aq[4], ak[4], av[4];
#pragma unroll
    for (int nt = 0; nt < 4; ++nt) {
        aq[nt] = floatx4{0.f, 0.f, 0.f, 0.f};
        ak[nt] = floatx4{0.f, 0.f, 0.f, 0.f};
        av[nt] = floatx4{0.f, 0.f, 0.f, 0.f};
    }

    for (int k0 = 0; k0 < 512; k0 += 64) {
#pragma unroll
        for (int i = 0; i < 2; ++i) {
            const int r  = i * 32 + srow0;
            const int cg = (sgrp ^ (r & 7)) << 3;     // inverse-swizzled source
            const int db = (i * 32 + w * 8) * 64;     // wave-uniform LDS base
            gload16(xb  + (size_t)(m0 + r) * 512 + k0 + cg, &As[db]);
            gload16(WqT + (size_t)(n0 + r) * 512 + k0 + cg, &Bq[db]);
            gload16(WkT + (size_t)(n0 + r) * 512 + k0 + cg, &Bk[db]);
            gload16(WvT + (size_t)(n0 + r) * 512 + k0 + cg, &Bv[db]);
        }
        __syncthreads();

#pragma unroll
        for (int kk = 0; kk < 2; ++kk) {
            const int arow = w * 16 + l15;
            const bf16x8 af = *reinterpret_cast<const bf16x8*>(
                &As[arow * 64 + (((kk * 4 + quad) ^ (arow & 7)) << 3)]);
#pragma unroll
            for (int nt = 0; nt < 4; ++nt) {
                const int brow = nt * 16 + l15;
                const int off  = brow * 64 + (((kk * 4 + quad) ^ (brow & 7)) << 3);
                aq[nt] = MFMA16(af, *reinterpret_cast<const bf16x8*>(&Bq[off]), aq[nt]);
                ak[nt] = MFMA16(af, *reinterpret_cast<const bf16x8*>(&Bk[off]), ak[nt]);
                av[nt] = MFMA16(af, *reinterpret_cast<const bf16x8*>(&Bv[off]), av[nt]);
            }
        }
        __syncthreads();
    }

    // Epilogue: Q,K row-major; V into Cs (transposed) then coalesced vbT write
#pragma unroll
    for (int nt = 0; nt < 4; ++nt) {
        const int col = n0 + nt * 16 + l15;
        const float bqv = bq[col], bkv = bk[col], bvv = bv[col];
#pragma unroll
        for (int r = 0; r < 4; ++r) {
            const int row = m0 + w * 16 + quad * 4 + r;
            qb[(size_t)row * 512 + col] = (__bf16)((aq[nt][r] + bqv) * 0.125f);
            kb[(size_t)row * 512 + col] = (__bf16)(ak[nt][r] + bkv);
            Cs[(nt * 16 + l15) * 80 + w * 16 + quad * 4 + r] = (__bf16)(av[nt][r] + bvv);
        }
    }
    __syncthreads();
    {
        const int bb = m0 >> 12;
        const int tb = m0 & 4095;
        __bf16* yb = vbT + (size_t)bb * 512 * 4096;
#pragma unroll
        for (int it = 0; it < 2; ++it) {
            const int flat = it * 2048 + tid * 8;
            const int pl = flat >> 6;
            const int c  = flat & 63;
            const bf16x8 vv = *reinterpret_cast<const bf16x8*>(&Cs[pl * 80 + c]);
            *reinterpret_cast<bf16x8*>(&yb[(size_t)(n0 + pl) * 4096 + tb + c]) = vv;
        }
    }
}

// ---------------------------------------------------------------------------
// Output GEMM: out[M x 512] = attended(bf16) WoT^T + bo (fp32 out).
// ---------------------------------------------------------------------------
__global__ __launch_bounds__(256, 2) void out_gemm(
    const __bf16* __restrict__ A, const __bf16* __restrict__ WT,
    const float* __restrict__ bias, float* __restrict__ Y)
{
    __shared__ __attribute__((aligned(16))) __bf16 As[64 * 64];
    __shared__ __attribute__((aligned(16))) __bf16 Bs[64 * 64];

    const int tid  = threadIdx.x;
    const int w    = tid >> 6;
    const int lane = tid & 63;
    const int quad = lane >> 4;
    const int l15  = lane & 15;
    const int fid  = blockIdx.x;
    const int n0   = (fid & 7) * 64;
    const int m0   = (fid >> 3) * 64;

    const int srow0 = w * 8 + (lane >> 3);
    const int sgrp  = lane & 7;

    floatx4 acc[4];
#pragma unroll
    for (int nt = 0; nt < 4; ++nt) acc[nt] = floatx4{0.f, 0.f, 0.f, 0.f};

    for (int k0 = 0; k0 < 512; k0 += 64) {
#pragma unroll
        for (int i = 0; i < 2; ++i) {
            const int r  = i * 32 + srow0;
            const int cg = (sgrp ^ (r & 7)) << 3;
            const int db = (i * 32 + w * 8) * 64;
            gload16(A  + (size_t)(m0 + r) * 512 + k0 + cg, &As[db]);
            gload16(WT + (size_t)(n0 + r) * 512 + k0 + cg, &Bs[db]);
        }
        __syncthreads();

#pragma unroll
        for (int kk = 0; kk < 2; ++kk) {
            const int arow = w * 16 + l15;
            const bf16x8 af = *reinterpret_cast<const bf16x8*>(
                &As[arow * 64 + (((kk * 4 + quad) ^ (arow & 7)) << 3)]);
#pragma unroll
            for (int nt = 0; nt < 4; ++nt) {
                const int brow = nt * 16 + l15;
                const bf16x8 bfv = *reinterpret_cast<const bf16x8*>(
                    &Bs[brow * 64 + (((kk * 4 + quad) ^ (brow & 7)) << 3)]);
                acc[nt] = MFMA16(af, bfv, acc[nt]);
            }
        }
        __syncthreads();
    }

#pragma unroll
    for (int nt = 0; nt < 4; ++nt) {
        const int col = n0 + nt * 16 + l15;
        const float bv = bias[col];
#pragma unroll
        for (int r = 0; r < 4; ++r) {
            const int row = m0 + w * 16 + quad * 4 + r;
            Y[(size_t)row * 512 + col] = acc[nt][r] + bv;
        }
    }
}

// ---------------------------------------------------------------------------
// Flash attention = R2's proven 2-phase counted-vmcnt schedule, scaled to
// QBLK=128 (8 waves, 512 thr) to HALVE K/V L2 traffic (each block re-reads
// its 4MB K/V half for 128 q-rows instead of 64 -> 2GB -> 1GB aggregate).
// Grid 256 blocks = 1/CU, single round; g=fid&7 -> (b,hb): 32 blocks per
// XCD group = exactly one XCD's CUs. Per-wave structure identical to R2:
// wave w owns q-rows w*16..+16, Pl is wave-private (no P barrier), counted
// vmcnt(4) (4 K-DMA + 4 V-DMA per wave in flight, never drained in-loop).
// ---------------------------------------------------------------------------
__global__ __launch_bounds__(512, 2) void flash_attn(
    const __bf16* __restrict__ q, const __bf16* __restrict__ k,
    const __bf16* __restrict__ vT, __bf16* __restrict__ pO,
    float* __restrict__ lP)
{
    __shared__ __bf16 Kt[32 * 520];    // [key][p], padded stride 520
    __shared__ __bf16 Vt[512 * 32];    // [p][key], unpadded + XOR swizzle
    __shared__ __bf16 Pl[8 * 16 * 40]; // per-wave P: [w*16+row][key], stride 40

    const int tid  = threadIdx.x;
    const int w    = tid >> 6;      // 0..7 = row group
    const int lane = tid & 63;
    const int quad = lane >> 4;
    const int l15  = lane & 15;

    const int fid = blockIdx.x;     // 0..255
    const int g   = fid & 7;        // XCD group = (batch, half)
    const int hb  = g & 1;
    const int b   = g >> 1;
    const int q0  = (fid >> 3) * 128;
    const size_t boff = (size_t)b * SEQ * 512;

    // Q fragments (pre-scaled by 0.125): rows q0 + w*16 + l15, A-layout
    bf16x8 qf[16];
    {
        const __bf16* qrow = q + boff + (size_t)(q0 + w * 16 + l15) * 512;
#pragma unroll
        for (int kk = 0; kk < 16; ++kk)
            qf[kk] = *reinterpret_cast<const bf16x8*>(qrow + kk * 32 + quad * 8);
    }

    floatx4 o[32];
#pragma unroll
    for (int i = 0; i < 32; ++i) o[i] = floatx4{0.f, 0.f, 0.f, 0.f};
    float lsum[4] = {0.f, 0.f, 0.f, 0.f};

    const __bf16* kB  = k + boff;
    const __bf16* vTb = vT + boff;
    const int tstart = hb * 2048;
    const int tend   = tstart + 2048;

    const int vprow = lane >> 2;                                  // 0..15
    const int vkoff = (((lane & 3) ^ ((lane >> 3) & 3)) << 3);    // pre-swz src

    // ---- prologue: issue K(t0) then V(t0) (4 + 4 DMAs per wave)
    {
        const __bf16* kbase = kB + (size_t)(tstart + w * 4) * 512 + lane * 8;
#pragma unroll
        for (int j = 0; j < 4; ++j)
            gload16(kbase + (size_t)j * 512, &Kt[(w * 4 + j) * 520]);
#pragma unroll
        for (int j = 0; j < 4; ++j) {
            const int p0 = (w * 4 + j) * 16;
            gload16(vTb + (size_t)(p0 + vprow) * 4096 + tstart + vkoff, &Vt[p0 * 32]);
        }
    }

    for (int t0 = tstart; t0 < tend; t0 += 32) {
        const int tn = (t0 + 32 < tend) ? t0 + 32 : t0;   // clamp: re-load last

        // ---- phase 1: QK^T on Kt(t); V(t) still in flight (4 outstanding)
        asm volatile("s_waitcnt vmcnt(4)" ::: "memory");
        __builtin_amdgcn_s_barrier();

        floatx4 sa0 = floatx4{0.f, 0.f, 0.f, 0.f};
        floatx4 sa1 = floatx4{0.f, 0.f, 0.f, 0.f};
        __builtin_amdgcn_s_setprio(1);
#pragma unroll
        for (int kk = 0; kk < 16; ++kk) {
            const bf16x8 kf0 = *reinterpret_cast<const bf16x8*>(
                &Kt[l15 * 520 + kk * 32 + quad * 8]);
            const bf16x8 kf1 = *reinterpret_cast<const bf16x8*>(
                &Kt[(16 + l15) * 520 + kk * 32 + quad * 8]);
            sa0 = MFMA16(qf[kk], kf0, sa0);
            sa1 = MFMA16(qf[kk], kf1, sa1);
        }
        __builtin_amdgcn_s_setprio(0);

        // P = exp(s), accumulate l, stash P (wave-private rows -> no barrier)
#pragma unroll
        for (int r = 0; r < 4; ++r) {
            const float p0 = __expf(sa0[r]);
            const float p1 = __expf(sa1[r]);
            lsum[r] += p0 + p1;
            Pl[(w * 16 + quad * 4 + r) * 40 + l15]      = (__bf16)p0;
            Pl[(w * 16 + quad * 4 + r) * 40 + 16 + l15] = (__bf16)p1;
        }

        __builtin_amdgcn_s_barrier();   // all waves done reading Kt(t)

        {   // issue K(t+1) over Kt
            const __bf16* kbase = kB + (size_t)(tn + w * 4) * 512 + lane * 8;
#pragma unroll
            for (int j = 0; j < 4; ++j)
                gload16(kbase + (size_t)j * 512, &Kt[(w * 4 + j) * 520]);
        }

        // ---- phase 2: PV on Vt(t); K(t+1) in flight (4 outstanding)
        asm volatile("s_waitcnt vmcnt(4)" ::: "memory");
        __builtin_amdgcn_s_barrier();

        const bf16x8 pf = *reinterpret_cast<const bf16x8*>(
            &Pl[(w * 16 + l15) * 40 + quad * 8]);
        const int vsw = ((quad ^ ((l15 >> 1) & 3)) << 3);
        __builtin_amdgcn_s_setprio(1);
#pragma unroll
        for (int pt = 0; pt < 32; ++pt) {
            const bf16x8 vf = *reinterpret_cast<const bf16x8*>(
                &Vt[(pt * 16 + l15) * 32 + vsw]);
            o[pt] = MFMA16(pf, vf, o[pt]);
        }
        __builtin_amdgcn_s_setprio(0);

        __builtin_amdgcn_s_barrier();   // all waves done reading Vt(t)

#pragma unroll
        for (int j = 0; j < 4; ++j) {   // issue V(t+1) over Vt
            const int p0 = (w * 4 + j) * 16;
            gload16(vTb + (size_t)(p0 + vprow) * 4096 + tn + vkoff, &Vt[p0 * 32]);
        }
    }
    asm volatile("s_waitcnt vmcnt(0)" ::: "memory");  // drain tail DMA

    // ---- final l (16-lane reduce) and partial writes
#pragma unroll
    for (int r = 0; r < 4; ++r) {
#pragma unroll
        for (int off = 1; off < 16; off <<= 1)
            lsum[r] += __shfl_xor(lsum[r], off);
    }
    const int rowbase = b * SEQ + q0 + w * 16 + quad * 4;
    if (l15 == 0) {
#pragma unroll
        for (int r = 0; r < 4; ++r)
            lP[(size_t)hb * MTOT + rowbase + r] = lsum[r];
    }
    __bf16* pOh = pO + (size_t)hb * MTOT * 512;
#pragma unroll
    for (int pt = 0; pt < 32; ++pt) {
#pragma unroll
        for (int r = 0; r < 4; ++r)
            pOh[(size_t)(rowbase + r) * 512 + pt * 16 + l15] = (__bf16)o[pt][r];
    }
}

// ---------------------------------------------------------------------------
// Merge the two key-half partials: att = (O0 + O1) / (l0 + l1)
// ---------------------------------------------------------------------------
__global__ __launch_bounds__(256) void merge_attn(
    const __bf16* __restrict__ pO, const float* __restrict__ lP,
    __bf16* __restrict__ att)
{
    const int gidx = blockIdx.x * 256 + threadIdx.x;  // 8-elem group
    const int row  = gidx >> 6;
    const int c8   = (gidx & 63) * 8;
    const float li = 1.0f / (lP[row] + lP[MTOT + row]);
    const bf16x8 a = *reinterpret_cast<const bf16x8*>(&pO[(size_t)row * 512 + c8]);
    const bf16x8 bvv = *reinterpret_cast<const bf16x8*>(
        &pO[((size_t)MTOT + row) * 512 + c8]);
    bf16x8 r8;
#pragma unroll
    for (int j = 0; j < 8; ++j)
        r8[j] = (__bf16)(((float)a[j] + (float)bvv[j]) * li);
    *reinterpret_cast<bf16x8*>(&att[(size_t)row * 512 + c8]) = r8;
}

// ---------------------------------------------------------------------------
extern "C" void kernel_launch(void* const* d_in, const int* in_sizes, int n_in,
                              void* d_out, int out_size, void* d_ws, size_t ws_size,
                              hipStream_t stream)
{
    (void)in_sizes; (void)n_in; (void)out_size; (void)ws_size;

    const float* x  = (const float*)d_in[0];
    const float* Wq = (const float*)d_in[1];
    const float* bq = (const float*)d_in[2];
    const float* Wk = (const float*)d_in[3];
    const float* bk = (const float*)d_in[4];
    const float* Wv = (const float*)d_in[5];
    const float* bv = (const float*)d_in[6];
    const float* Wo = (const float*)d_in[7];
    const float* bo = (const float*)d_in[8];
    float* out = (float*)d_out;

    // ws (48.1 MB): qb, kb, vbT (16 MB each) + lP. Scratch that is dead by
    // the time its region is overwritten:
    //   xb + WqT/WkT/WvT live in d_out (overwritten by pO during flash)
    //   WoT lives in kb (kb dead after flash)
    //   ab (attended) overlays qb (dead after flash)
    __bf16* qb  = (__bf16*)d_ws;
    __bf16* kb  = qb  + (size_t)MTOT * 512;
    __bf16* vbT = kb  + (size_t)MTOT * 512;
    float*  lP  = (float*)(vbT + (size_t)MTOT * 512);
    __bf16* pO  = (__bf16*)d_out;
    __bf16* ab  = qb;

    __bf16* xb  = (__bf16*)d_out;
    __bf16* WqT = xb  + (size_t)MTOT * 512;
    __bf16* WkT = WqT + 512 * 512;
    __bf16* WvT = WkT + 512 * 512;
    __bf16* WoT = kb;

    cvt_x<<<MTOT * 512 / 2048, 256, 0, stream>>>(x, xb);
    transpose_w<<<64, 256, 0, stream>>>(Wq, WqT);
    transpose_w<<<64, 256, 0, stream>>>(Wk, WkT);
    transpose_w<<<64, 256, 0, stream>>>(Wv, WvT);

    qkv_gemm<<<2048, 256, 0, stream>>>(xb, WqT, bq, WkT, bk, WvT, bv, qb, kb, vbT);

    flash_attn<<<256, 512, 0, stream>>>(qb, kb, vbT, pO, lP);

    transpose_w<<<64, 256, 0, stream>>>(Wo, WoT);
    merge_attn<<<MTOT * 64 / 256, 256, 0, stream>>>(pO, lP, ab);

    out_gemm<<<2048, 256, 0, stream>>>(ab, WoT, bo, out);
}